// Round 10
// baseline (2377.015 us; speedup 1.0000x reference)
//
#include <hip/hip_runtime.h>
#include <hip/hip_bf16.h>
#include <cstdint>
#include <cstddef>

#define M_TOTAL 16384   // WORLD_SIZE * M_LOCAL
#define K_DIM   4096
#define N_DIM   4096

typedef __attribute__((ext_vector_type(8))) short s16x8;
typedef __attribute__((ext_vector_type(4))) float f32x4;
typedef unsigned short ushort_t;

// ---------- fp32 -> bf16 round-to-nearest-even ----------
__device__ __forceinline__ ushort_t f2bf(float x) {
  unsigned u = __float_as_uint(x);
  return (ushort_t)((u + 0x7fffu + ((u >> 16) & 1u)) >> 16);
}

// ---------- cast A [M,K] fp32 -> bf16, 8 elems/thread ----------
__global__ __launch_bounds__(256) void cast_kernel(const float* __restrict__ in,
                                                   ushort_t* __restrict__ out,
                                                   long n8) {
  long i = (long)blockIdx.x * 256 + threadIdx.x;
  if (i >= n8) return;
  const f32x4* p = (const f32x4*)in + i * 2;
  f32x4 a = p[0], b = p[1];
  union { s16x8 v; ushort_t u[8]; } r;
  r.u[0] = f2bf(a.x); r.u[1] = f2bf(a.y); r.u[2] = f2bf(a.z); r.u[3] = f2bf(a.w);
  r.u[4] = f2bf(b.x); r.u[5] = f2bf(b.y); r.u[6] = f2bf(b.z); r.u[7] = f2bf(b.w);
  *((s16x8*)out + i) = r.v;
}

// ---------- transpose+cast W [K,N] fp32 -> Bt [N,K] bf16 ----------
__global__ __launch_bounds__(256) void transpose_cast_kernel(const float* __restrict__ B,
                                                             ushort_t* __restrict__ Bt) {
  __shared__ float tile[64][65];
  int nbx = N_DIM / 64;
  int n0 = (blockIdx.x % nbx) * 64;
  int k0 = (blockIdx.x / nbx) * 64;
  int tx = threadIdx.x & 63;
  int ty = threadIdx.x >> 6;
#pragma unroll
  for (int i = 0; i < 64; i += 4)
    tile[ty + i][tx] = B[(size_t)(k0 + ty + i) * N_DIM + n0 + tx];
  __syncthreads();
#pragma unroll
  for (int i = 0; i < 64; i += 4)
    Bt[(size_t)(n0 + ty + i) * K_DIM + k0 + tx] = f2bf(tile[tx][ty + i]);
}

// ============================================================================
// 256x256 bf16 GEMM — round 10: R9 structure (1 barrier/K-tile, B triple-buf,
// counted VMW4) + WAVE ANTI-PHASE: HW maps wave i -> SIMD i&3, so each SIMD
// hosts a wm=0 and a wm=1 wave. wm=0 order: [read q0+B; MFMA q0; read q1;
// MFMA q1]; wm=1 order: [read q1+B; MFMA q1; read q0; MFMA q0]. While one
// wave of a SIMD is in its MFMA cluster its partner is in its read cluster ->
// LDS unit and matrix pipe fed simultaneously (breaks the CU-wide lockstep
// that left LDS ~2300cy/K-tile unhidden; R6/R9 showed per-wave interleave and
// barrier removal alone are null).
// Same reads/stages/waits as R9, reordered within a published interval:
// WAR/RAW ledger unchanged. Register live-set unchanged (a[], b0, b1).
// ============================================================================
#define BM 256
#define BN 256
#define BK 64
#define NTILE (K_DIM / BK)   // 64

__device__ __forceinline__ void load_lds16(const ushort_t* g, ushort_t* l) {
  __builtin_amdgcn_global_load_lds(
      (const __attribute__((address_space(1))) unsigned int*)g,
      (__attribute__((address_space(3))) unsigned int*)l, 16, 0, 0);
}

#define BAR __builtin_amdgcn_s_barrier()
#define VMW4 asm volatile("s_waitcnt vmcnt(4)" ::: "memory")
#define VMW0 asm volatile("s_waitcnt vmcnt(0)" ::: "memory")
#define PRIO1 __builtin_amdgcn_s_setprio(1)
#define PRIO0 __builtin_amdgcn_s_setprio(0)

#define STAGE_A(dst, h, t) do { \
    load_lds16(pA + (size_t)((h) * 128) * K_DIM + (size_t)(t) * 64, (dst) + (h) * 8192); \
    load_lds16(pA + (size_t)((h) * 128 + 64) * K_DIM + (size_t)(t) * 64, (dst) + (h) * 8192 + 4096); } while (0)
#define STAGE_B(dst, h, t) do { \
    load_lds16(pB + (size_t)((h) * 128) * K_DIM + (size_t)(t) * 64, (dst) + (h) * 8192); \
    load_lds16(pB + (size_t)((h) * 128 + 64) * K_DIM + (size_t)(t) * 64, (dst) + (h) * 8192 + 4096); } while (0)

#define READ_A(AB, arr, q) do { \
    _Pragma("unroll") for (int mf = 0; mf < 4; ++mf) { \
      int ia = aBase + ((q) * 4 + mf) * 1024; \
      arr[mf][0] = *(const s16x8*)&lds_a[AB][ia]; \
      arr[mf][1] = *(const s16x8*)&lds_a[AB][ia ^ 32]; } } while (0)
#define READ_B(BB, arr, nh) do { \
    _Pragma("unroll") for (int nf = 0; nf < 2; ++nf) { \
      int ib = bBase + ((nh) * 2 + nf) * 1024; \
      arr[nf][0] = *(const s16x8*)&lds_b[BB][ib]; \
      arr[nf][1] = *(const s16x8*)&lds_b[BB][ib ^ 32]; } } while (0)

// 16 MFMA, ks outermost: 8 independent between accumulator reuse.
#define MFMA_Q(arr_a, arr_b, m0, n0) do { \
    _Pragma("unroll") for (int ks = 0; ks < 2; ++ks) \
    _Pragma("unroll") for (int mf = 0; mf < 4; ++mf) \
    _Pragma("unroll") for (int nf = 0; nf < 2; ++nf) \
      acc[(m0) + mf][(n0) + nf] = __builtin_amdgcn_mfma_f32_16x16x32_bf16( \
          arr_a[mf][ks], arr_b[nf][ks], acc[(m0) + mf][(n0) + nf], 0, 0, 0); } while (0)

// One K-tile, anti-phased by wm. Stage targets/tiles identical in both arms.
#define TILE_FULL(AB, BB, ABN, BBN, TA, TB) do { \
    if (wm == 0) { \
      READ_A(AB, a, 0); READ_B(BB, b0, 0); READ_B(BB, b1, 1); \
      STAGE_A(aP##ABN, 0, (TA)); STAGE_A(aP##ABN, 1, (TA)); \
      PRIO1; MFMA_Q(a, b0, 0, 0); MFMA_Q(a, b1, 0, 2); PRIO0; \
      READ_A(AB, a, 1); \
      STAGE_B(bP##BBN, 0, (TB)); STAGE_B(bP##BBN, 1, (TB)); \
      PRIO1; MFMA_Q(a, b1, 4, 2); MFMA_Q(a, b0, 4, 0); PRIO0; \
    } else { \
      READ_A(AB, a, 1); READ_B(BB, b1, 1); READ_B(BB, b0, 0); \
      STAGE_A(aP##ABN, 0, (TA)); STAGE_A(aP##ABN, 1, (TA)); \
      PRIO1; MFMA_Q(a, b1, 4, 2); MFMA_Q(a, b0, 4, 0); PRIO0; \
      READ_A(AB, a, 0); \
      STAGE_B(bP##BBN, 0, (TB)); STAGE_B(bP##BBN, 1, (TB)); \
      PRIO1; MFMA_Q(a, b0, 0, 0); MFMA_Q(a, b1, 0, 2); PRIO0; \
    } \
    VMW4; BAR; \
  } while (0)

__global__ __launch_bounds__(512, 2)
void gemm_antiphase(const ushort_t* __restrict__ A, const ushort_t* __restrict__ Bt,
                    const float* __restrict__ bias, float* __restrict__ C) {
  __shared__ ushort_t lds_a[2][16384];   // 64 KiB
  __shared__ ushort_t lds_b[3][16384];   // 96 KiB  (total 160 KiB)

  // bijective XCD swizzle (nwg = 1024, % 8 == 0)
  int nwg = gridDim.x;
  int wg  = blockIdx.x;
  int swz = (wg & 7) * (nwg >> 3) + (wg >> 3);
  int bm = (swz >> 4) << 8;
  int bn = (swz & 15) << 8;

  int tid = threadIdx.x;
  int wid = tid >> 6;
  int l   = tid & 63;
  int wm = wid >> 2, wn = wid & 3;

  // staging: lane covers global (row = base + wid*8 + (l>>3), slot = (l&7)^(row&7))
  int sg8 = ((l & 7) ^ ((l >> 3) & 7)) << 3;
  const ushort_t* pA = A  + (size_t)(bm + wid * 8 + (l >> 3)) * K_DIM + sg8;
  const ushort_t* pB = Bt + (size_t)(bn + wid * 8 + (l >> 3)) * K_DIM + sg8;
  ushort_t* aP0 = &lds_a[0][wid * 512];
  ushort_t* aP1 = &lds_a[1][wid * 512];
  ushort_t* bP0 = &lds_b[0][wid * 512];
  ushort_t* bP1 = &lds_b[1][wid * 512];
  ushort_t* bP2 = &lds_b[2][wid * 512];

  // read bases: row = (wm*128 | mf*16 | (l&15)); slot = (ks*4 | (l>>4)) ^ (l&7)
  int slot0 = (l >> 4) ^ (l & 7);
  int aBase = (wm * 128 + (l & 15)) * 64 + slot0 * 8;
  int bBase = (wn * 64 + (l & 15)) * 64 + slot0 * 8;

  f32x4 acc[8][4];
#pragma unroll
  for (int mf = 0; mf < 8; ++mf)
#pragma unroll
    for (int nf = 0; nf < 4; ++nf) acc[mf][nf] = (f32x4){0.f, 0.f, 0.f, 0.f};

  s16x8 a[4][2], b0[2][2], b1[2][2];

  // prologue: A(0)->Ab0, B(0)->Bb0 (8 loads), B(1)->Bb1 (4);
  // VMW4 drains A(0),B(0), leaves B(1) in flight; BAR publishes tile 0.
  STAGE_A(aP0, 0, 0); STAGE_A(aP0, 1, 0);
  STAGE_B(bP0, 0, 0); STAGE_B(bP0, 1, 0);
  STAGE_B(bP1, 0, 1); STAGE_B(bP1, 1, 1);
  VMW4; BAR;

  // t = 0..59 (6-tile period: A t&1, B t%3)
  for (int r = 0; r < 10; ++r) {
    int t = 6 * r;
    TILE_FULL(0, 0, 1, 2, t + 1, t + 2);   // t%6==0
    TILE_FULL(1, 1, 0, 0, t + 2, t + 3);   // 1
    TILE_FULL(0, 2, 1, 1, t + 3, t + 4);   // 2
    TILE_FULL(1, 0, 0, 2, t + 4, t + 5);   // 3
    TILE_FULL(0, 1, 1, 0, t + 5, t + 6);   // 4
    TILE_FULL(1, 2, 0, 1, t + 6, t + 7);   // 5
  }
  // t=60 (Ab0,Bb0): stage A(61)->Ab1, B(62)->Bb2
  TILE_FULL(0, 0, 1, 2, 61, 62);
  // t=61 (Ab1,Bb1): stage A(62)->Ab0, B(63)->Bb0
  TILE_FULL(1, 1, 0, 0, 62, 63);
  // t=62 (Ab0,Bb2): stage A(63)->Ab1; full drain (anti-phased)
  {
    if (wm == 0) {
      READ_A(0, a, 0); READ_B(2, b0, 0); READ_B(2, b1, 1);
      STAGE_A(aP1, 0, 63); STAGE_A(aP1, 1, 63);
      PRIO1; MFMA_Q(a, b0, 0, 0); MFMA_Q(a, b1, 0, 2); PRIO0;
      READ_A(0, a, 1);
      PRIO1; MFMA_Q(a, b1, 4, 2); MFMA_Q(a, b0, 4, 0); PRIO0;
    } else {
      READ_A(0, a, 1); READ_B(2, b1, 1); READ_B(2, b0, 0);
      STAGE_A(aP1, 0, 63); STAGE_A(aP1, 1, 63);
      PRIO1; MFMA_Q(a, b1, 4, 2); MFMA_Q(a, b0, 4, 0); PRIO0;
      READ_A(0, a, 0);
      PRIO1; MFMA_Q(a, b0, 0, 0); MFMA_Q(a, b1, 0, 2); PRIO0;
    }
    VMW0; BAR;   // A(63),B(63) landed + published
  }
  // t=63 (Ab1,Bb0): reads only (anti-phased)
  {
    if (wm == 0) {
      READ_A(1, a, 0); READ_B(0, b0, 0); READ_B(0, b1, 1);
      PRIO1; MFMA_Q(a, b0, 0, 0); MFMA_Q(a, b1, 0, 2); PRIO0;
      READ_A(1, a, 1);
      PRIO1; MFMA_Q(a, b1, 4, 2); MFMA_Q(a, b0, 4, 0); PRIO0;
    } else {
      READ_A(1, a, 1); READ_B(0, b1, 1); READ_B(0, b0, 0);
      PRIO1; MFMA_Q(a, b1, 4, 2); MFMA_Q(a, b0, 4, 0); PRIO0;
      READ_A(1, a, 0);
      PRIO1; MFMA_Q(a, b0, 0, 0); MFMA_Q(a, b1, 0, 2); PRIO0;
    }
  }

  // epilogue: C/D layout col = lane&15, row = (lane>>4)*4 + j
  int r0 = bm + wm * 128 + ((l >> 4) << 2);
  int c0 = bn + wn * 64 + (l & 15);
#pragma unroll
  for (int nf = 0; nf < 4; ++nf) {
    float bv = bias[c0 + nf * 16];
#pragma unroll
    for (int mf = 0; mf < 8; ++mf) {
#pragma unroll
      for (int jj = 0; jj < 4; ++jj)
        C[(size_t)(r0 + mf * 16 + jj) * N_DIM + (c0 + nf * 16)] = acc[mf][nf][jj] + bv;
    }
  }
}

// ---------- naive fp32 fallback (only if ws_size too small) ----------
__global__ __launch_bounds__(256)
void gemm_naive(const float* __restrict__ A, const float* __restrict__ B,
                const float* __restrict__ bias, float* __restrict__ C) {
  __shared__ float As[64][17];
  __shared__ float Bs[16][65];
  int nbn = N_DIM / 64;
  int m0 = (blockIdx.x / nbn) * 64;
  int n0 = (blockIdx.x % nbn) * 64;
  int tid = threadIdx.x;
  int tx = tid & 15, ty = tid >> 4;
  float acc[4][4] = {};
  for (int k0 = 0; k0 < K_DIM; k0 += 16) {
    __syncthreads();
#pragma unroll
    for (int e = tid * 4, i = 0; i < 4; ++i) {
      int idx = e + i;
      int r = idx >> 4, k = idx & 15;
      As[r][k] = A[(size_t)(m0 + r) * K_DIM + k0 + k];
    }
#pragma unroll
    for (int e = tid * 4, i = 0; i < 4; ++i) {
      int idx = e + i;
      int k = idx >> 6, n = idx & 63;
      Bs[k][n] = B[(size_t)(k0 + k) * N_DIM + n0 + n];
    }
    __syncthreads();
#pragma unroll
    for (int kk = 0; kk < 16; ++kk)
#pragma unroll
      for (int i = 0; i < 4; ++i)
#pragma unroll
        for (int j = 0; j < 4; ++j)
          acc[i][j] += As[ty * 4 + i][kk] * Bs[kk][tx * 4 + j];
  }
#pragma unroll
  for (int i = 0; i < 4; ++i)
#pragma unroll
    for (int j = 0; j < 4; ++j) {
      int r = m0 + ty * 4 + i, c = n0 + tx * 4 + j;
      C[(size_t)r * N_DIM + c] = acc[i][j] + bias[c];
    }
}

extern "C" void kernel_launch(void* const* d_in, const int* in_sizes, int n_in,
                              void* d_out, int out_size, void* d_ws, size_t ws_size,
                              hipStream_t stream) {
  const float* A32  = (const float*)d_in[0];
  const float* W32  = (const float*)d_in[1];
  const float* bias = (const float*)d_in[2];
  float* C = (float*)d_out;

  const size_t needA = (size_t)M_TOTAL * K_DIM * sizeof(ushort_t); // 128 MiB
  const size_t needB = (size_t)N_DIM * K_DIM * sizeof(ushort_t);   // 32 MiB

  if (ws_size >= needA + needB) {
    ushort_t* Abf = (ushort_t*)d_ws;
    ushort_t* Btb = (ushort_t*)((char*)d_ws + needA);
    long n8 = (long)M_TOTAL * K_DIM / 8;
    cast_kernel<<<(int)((n8 + 255) / 256), 256, 0, stream>>>(A32, Abf, n8);
    transpose_cast_kernel<<<(K_DIM / 64) * (N_DIM / 64), 256, 0, stream>>>(W32, Btb);
    gemm_antiphase<<<(M_TOTAL / BM) * (N_DIM / BN), 512, 0, stream>>>(Abf, Btb, bias, C);
  } else {
    gemm_naive<<<(M_TOTAL / 64) * (N_DIM / 64), 256, 0, stream>>>(A32, W32, bias, C);
  }
}

// Round 11
// 692.197 us; speedup vs baseline: 3.4340x; 3.4340x over previous
//
#include <hip/hip_runtime.h>
#include <hip/hip_bf16.h>
#include <cstdint>
#include <cstddef>

#define M_TOTAL 16384   // WORLD_SIZE * M_LOCAL
#define K_DIM   4096
#define N_DIM   4096

typedef __attribute__((ext_vector_type(8))) short s16x8;
typedef __attribute__((ext_vector_type(4))) float f32x4;
typedef unsigned short ushort_t;

// ---------- fp32 -> bf16 round-to-nearest-even ----------
__device__ __forceinline__ ushort_t f2bf(float x) {
  unsigned u = __float_as_uint(x);
  return (ushort_t)((u + 0x7fffu + ((u >> 16) & 1u)) >> 16);
}

// ---------- cast A [M,K] fp32 -> bf16, 8 elems/thread ----------
__global__ __launch_bounds__(256) void cast_kernel(const float* __restrict__ in,
                                                   ushort_t* __restrict__ out,
                                                   long n8) {
  long i = (long)blockIdx.x * 256 + threadIdx.x;
  if (i >= n8) return;
  const f32x4* p = (const f32x4*)in + i * 2;
  f32x4 a = p[0], b = p[1];
  union { s16x8 v; ushort_t u[8]; } r;
  r.u[0] = f2bf(a.x); r.u[1] = f2bf(a.y); r.u[2] = f2bf(a.z); r.u[3] = f2bf(a.w);
  r.u[4] = f2bf(b.x); r.u[5] = f2bf(b.y); r.u[6] = f2bf(b.z); r.u[7] = f2bf(b.w);
  *((s16x8*)out + i) = r.v;
}

// ---------- transpose+cast W [K,N] fp32 -> Bt [N,K] bf16 ----------
__global__ __launch_bounds__(256) void transpose_cast_kernel(const float* __restrict__ B,
                                                             ushort_t* __restrict__ Bt) {
  __shared__ float tile[64][65];
  int nbx = N_DIM / 64;
  int n0 = (blockIdx.x % nbx) * 64;
  int k0 = (blockIdx.x / nbx) * 64;
  int tx = threadIdx.x & 63;
  int ty = threadIdx.x >> 6;
#pragma unroll
  for (int i = 0; i < 64; i += 4)
    tile[ty + i][tx] = B[(size_t)(k0 + ty + i) * N_DIM + n0 + tx];
  __syncthreads();
#pragma unroll
  for (int i = 0; i < 64; i += 4)
    Bt[(size_t)(n0 + ty + i) * K_DIM + k0 + tx] = f2bf(tile[tx][ty + i]);
}

// ============================================================================
// 128x256 bf16 GEMM — round 11: 2 BLOCKS/CU (cross-block TLP hides the
// barrier/drain bubble that 1-block/CU R7 cannot: while block A waits at
// s_barrier, block B's waves issue MFMA/LDS).
//   tile 128x256, BK=32, 512 thr = 8 waves (2M x 4N), wave-tile 64x64:
//   acc 4x4 f32x4 = 64 VGPR; a[4]+b[4] = 32 -> ~116 total, fits 128 at
//   __launch_bounds__(512,4). LDS: triple-buffered A(8K)+B(16K) = 72 KB
//   -> 2 blocks/CU (VGPR-limited).
// Swizzle (4 slots/row, re-derived): pslot = kgrp ^ ((row>>1)&3) -> exactly
// 2-way bank aliasing on ds_read_b128 (free, m136). Stage: linear dest
// global_load_lds + inverse-permuted source (rule #21):
//   lane l covers (row = l>>2, pslot = l&3) -> logical slot (l&3)^((l>>3)&3).
// Ledger: tile t reads buf(t%3); stages tile t+2 -> buf((t+2)%3) (3 issues/
// wave: A x1, B x2); VMW3 drains t+1 (issued last tile), leaves t+2 counted
// in flight; BAR publishes. WAR: buf((t+2)%3) last read at t-1, published by
// BAR(t-1). Prologue stages t0,t1; peel t=126 (VMW0) and t=127.
// ============================================================================
#define BM 128
#define BN 256
#define BK 32
#define NT (K_DIM / BK)    // 128 K-tiles

__device__ __forceinline__ void load_lds16(const ushort_t* g, ushort_t* l) {
  __builtin_amdgcn_global_load_lds(
      (const __attribute__((address_space(1))) unsigned int*)g,
      (__attribute__((address_space(3))) unsigned int*)l, 16, 0, 0);
}

#define BAR __builtin_amdgcn_s_barrier()
#define VMW3 asm volatile("s_waitcnt vmcnt(3)" ::: "memory")
#define VMW0 asm volatile("s_waitcnt vmcnt(0)" ::: "memory")
#define PRIO1 __builtin_amdgcn_s_setprio(1)
#define PRIO0 __builtin_amdgcn_s_setprio(0)

// stage tile T: A 1 issue + B 2 issues per wave (3 total)
#define STAGE(aD, bD, T) do { \
    load_lds16(pA  + (size_t)(T) * 32, (aD)); \
    load_lds16(pB0 + (size_t)(T) * 32, (bD)); \
    load_lds16(pB1 + (size_t)(T) * 32, (bD) + 512); } while (0)

// read 4 A-frags + 4 B-frags (8 x ds_read_b128, 2-way-free banking)
#define READ(BUF) do { \
    _Pragma("unroll") for (int mf = 0; mf < 4; ++mf) \
      a[mf] = *(const s16x8*)&lds_a[BUF][aBase + mf * 512]; \
    _Pragma("unroll") for (int nf = 0; nf < 4; ++nf) \
      b[nf] = *(const s16x8*)&lds_b[BUF][bBase + nf * 512]; } while (0)

// 16 MFMA, all-independent accumulators
#define MFMA16 do { \
    _Pragma("unroll") for (int mf = 0; mf < 4; ++mf) \
    _Pragma("unroll") for (int nf = 0; nf < 4; ++nf) \
      acc[mf][nf] = __builtin_amdgcn_mfma_f32_16x16x32_bf16( \
          a[mf], b[nf], acc[mf][nf], 0, 0, 0); } while (0)

#define TILE(BUF, aD, bD, T) do { \
    READ(BUF); \
    STAGE(aD, bD, (T)); \
    PRIO1; MFMA16; PRIO0; \
    VMW3; BAR; } while (0)

__global__ __launch_bounds__(512, 4)
void gemm_2blk(const ushort_t* __restrict__ A, const ushort_t* __restrict__ Bt,
               const float* __restrict__ bias, float* __restrict__ C) {
  __shared__ ushort_t lds_a[3][4096];   // 24 KiB
  __shared__ ushort_t lds_b[3][8192];   // 48 KiB  (72 KiB total -> 2 blocks/CU)

  // bijective XCD swizzle (nwg = 2048, % 8 == 0)
  int nwg = gridDim.x;
  int wg  = blockIdx.x;
  int swz = (wg & 7) * (nwg >> 3) + (wg >> 3);
  int bm = (swz >> 4) << 7;    // /16 n-tiles, *128
  int bn = (swz & 15) << 8;    // *256

  int tid = threadIdx.x;
  int wid = tid >> 6;
  int l   = tid & 63;
  int wm = wid >> 2, wn = wid & 3;

  // staging source: lane l covers (row = base + l>>2, pslot = l&3);
  // logical slot = (l&3) ^ ((l>>3)&3)  [inverse of pslot = slot ^ ((row>>1)&3)]
  int sg = ((l & 3) ^ ((l >> 3) & 3)) << 3;
  const ushort_t* pA  = A  + (size_t)(bm + wid * 16 + (l >> 2)) * K_DIM + sg;
  const ushort_t* pB0 = Bt + (size_t)(bn + wid * 32 + (l >> 2)) * K_DIM + sg;
  const ushort_t* pB1 = Bt + (size_t)(bn + wid * 32 + 16 + (l >> 2)) * K_DIM + sg;
  // per-wave LDS dests (linear, ushort units)
  ushort_t* aD0 = &lds_a[0][wid * 512];
  ushort_t* aD1 = &lds_a[1][wid * 512];
  ushort_t* aD2 = &lds_a[2][wid * 512];
  ushort_t* bD0 = &lds_b[0][wid * 1024];
  ushort_t* bD1 = &lds_b[1][wid * 1024];
  ushort_t* bD2 = &lds_b[2][wid * 1024];

  // read bases: row = grp*64 + frag*16 + (l&15); pslot = (l>>4) ^ ((row>>1)&3)
  // frag*16 doesn't touch (row>>1)&3 -> pslot0 = (l>>4) ^ ((l>>1)&3)
  int pslot0 = (l >> 4) ^ ((l >> 1) & 3);
  int aBase = (wm * 64 + (l & 15)) * 32 + pslot0 * 8;
  int bBase = (wn * 64 + (l & 15)) * 32 + pslot0 * 8;

  f32x4 acc[4][4];
#pragma unroll
  for (int mf = 0; mf < 4; ++mf)
#pragma unroll
    for (int nf = 0; nf < 4; ++nf) acc[mf][nf] = (f32x4){0.f, 0.f, 0.f, 0.f};

  s16x8 a[4], b[4];

  // prologue: stage t0 -> buf0, t1 -> buf1 (6 issues); drain t0 (leave t1); publish
  STAGE(aD0, bD0, 0);
  STAGE(aD1, bD1, 1);
  VMW3; BAR;

  // tiles 0..125 in 42 x 3 (buffer period 3)
  for (int r = 0; r < 42; ++r) {
    int t = 3 * r;
    TILE(0, aD2, bD2, t + 2);
    TILE(1, aD0, bD0, t + 3);
    TILE(2, aD1, bD1, t + 4);
  }
  // t=126 (buf0): no stage; full drain for t=127
  {
    READ(0);
    PRIO1; MFMA16; PRIO0;
    VMW0; BAR;
  }
  // t=127 (buf1): read only
  {
    READ(1);
    PRIO1; MFMA16; PRIO0;
  }

  // epilogue: C/D layout col = lane&15, row = (lane>>4)*4 + jj
  int r0 = bm + wm * 64 + ((l >> 4) << 2);
  int c0 = bn + wn * 64 + (l & 15);
#pragma unroll
  for (int nf = 0; nf < 4; ++nf) {
    float bv = bias[c0 + nf * 16];
#pragma unroll
    for (int mf = 0; mf < 4; ++mf) {
#pragma unroll
      for (int jj = 0; jj < 4; ++jj)
        C[(size_t)(r0 + mf * 16 + jj) * N_DIM + (c0 + nf * 16)] = acc[mf][nf][jj] + bv;
    }
  }
}

// ---------- naive fp32 fallback (only if ws_size too small) ----------
__global__ __launch_bounds__(256)
void gemm_naive(const float* __restrict__ A, const float* __restrict__ B,
                const float* __restrict__ bias, float* __restrict__ C) {
  __shared__ float As[64][17];
  __shared__ float Bs[16][65];
  int nbn = N_DIM / 64;
  int m0 = (blockIdx.x / nbn) * 64;
  int n0 = (blockIdx.x % nbn) * 64;
  int tid = threadIdx.x;
  int tx = tid & 15, ty = tid >> 4;
  float acc[4][4] = {};
  for (int k0 = 0; k0 < K_DIM; k0 += 16) {
    __syncthreads();
#pragma unroll
    for (int e = tid * 4, i = 0; i < 4; ++i) {
      int idx = e + i;
      int r = idx >> 4, k = idx & 15;
      As[r][k] = A[(size_t)(m0 + r) * K_DIM + k0 + k];
    }
#pragma unroll
    for (int e = tid * 4, i = 0; i < 4; ++i) {
      int idx = e + i;
      int k = idx >> 6, n = idx & 63;
      Bs[k][n] = B[(size_t)(k0 + k) * N_DIM + n0 + n];
    }
    __syncthreads();
#pragma unroll
    for (int kk = 0; kk < 16; ++kk)
#pragma unroll
      for (int i = 0; i < 4; ++i)
#pragma unroll
        for (int j = 0; j < 4; ++j)
          acc[i][j] += As[ty * 4 + i][kk] * Bs[kk][tx * 4 + j];
  }
#pragma unroll
  for (int i = 0; i < 4; ++i)
#pragma unroll
    for (int j = 0; j < 4; ++j) {
      int r = m0 + ty * 4 + i, c = n0 + tx * 4 + j;
      C[(size_t)r * N_DIM + c] = acc[i][j] + bias[c];
    }
}

extern "C" void kernel_launch(void* const* d_in, const int* in_sizes, int n_in,
                              void* d_out, int out_size, void* d_ws, size_t ws_size,
                              hipStream_t stream) {
  const float* A32  = (const float*)d_in[0];
  const float* W32  = (const float*)d_in[1];
  const float* bias = (const float*)d_in[2];
  float* C = (float*)d_out;

  const size_t needA = (size_t)M_TOTAL * K_DIM * sizeof(ushort_t); // 128 MiB
  const size_t needB = (size_t)N_DIM * K_DIM * sizeof(ushort_t);   // 32 MiB

  if (ws_size >= needA + needB) {
    ushort_t* Abf = (ushort_t*)d_ws;
    ushort_t* Btb = (ushort_t*)((char*)d_ws + needA);
    long n8 = (long)M_TOTAL * K_DIM / 8;
    cast_kernel<<<(int)((n8 + 255) / 256), 256, 0, stream>>>(A32, Abf, n8);
    transpose_cast_kernel<<<(K_DIM / 64) * (N_DIM / 64), 256, 0, stream>>>(W32, Btb);
    gemm_2blk<<<(M_TOTAL / BM) * (N_DIM / BN), 512, 0, stream>>>(Abf, Btb, bias, C);
  } else {
    gemm_naive<<<(M_TOTAL / 64) * (N_DIM / 64), 256, 0, stream>>>(A32, W32, bias, C);
  }
}

// Round 12
// 552.787 us; speedup vs baseline: 4.3001x; 1.2522x over previous
//
#include <hip/hip_runtime.h>
#include <hip/hip_bf16.h>
#include <cstdint>
#include <cstddef>

#define M_TOTAL 16384   // WORLD_SIZE * M_LOCAL
#define K_DIM   4096
#define N_DIM   4096

typedef __attribute__((ext_vector_type(8))) short s16x8;
typedef __attribute__((ext_vector_type(4))) float f32x4;
typedef unsigned short ushort_t;

// ---------- fp32 -> bf16 round-to-nearest-even ----------
__device__ __forceinline__ ushort_t f2bf(float x) {
  unsigned u = __float_as_uint(x);
  return (ushort_t)((u + 0x7fffu + ((u >> 16) & 1u)) >> 16);
}

// ---------- cast A [M,K] fp32 -> bf16, 8 elems/thread ----------
__global__ __launch_bounds__(256) void cast_kernel(const float* __restrict__ in,
                                                   ushort_t* __restrict__ out,
                                                   long n8) {
  long i = (long)blockIdx.x * 256 + threadIdx.x;
  if (i >= n8) return;
  const f32x4* p = (const f32x4*)in + i * 2;
  f32x4 a = p[0], b = p[1];
  union { s16x8 v; ushort_t u[8]; } r;
  r.u[0] = f2bf(a.x); r.u[1] = f2bf(a.y); r.u[2] = f2bf(a.z); r.u[3] = f2bf(a.w);
  r.u[4] = f2bf(b.x); r.u[5] = f2bf(b.y); r.u[6] = f2bf(b.z); r.u[7] = f2bf(b.w);
  *((s16x8*)out + i) = r.v;
}

// ---------- transpose+cast W [K,N] fp32 -> Bt [N,K] bf16 ----------
__global__ __launch_bounds__(256) void transpose_cast_kernel(const float* __restrict__ B,
                                                             ushort_t* __restrict__ Bt) {
  __shared__ float tile[64][65];
  int nbx = N_DIM / 64;
  int n0 = (blockIdx.x % nbx) * 64;
  int k0 = (blockIdx.x / nbx) * 64;
  int tx = threadIdx.x & 63;
  int ty = threadIdx.x >> 6;
#pragma unroll
  for (int i = 0; i < 64; i += 4)
    tile[ty + i][tx] = B[(size_t)(k0 + ty + i) * N_DIM + n0 + tx];
  __syncthreads();
#pragma unroll
  for (int i = 0; i < 64; i += 4)
    Bt[(size_t)(n0 + ty + i) * K_DIM + k0 + tx] = f2bf(tile[tx][ty + i]);
}

// ============================================================================
// 256x256 bf16 GEMM — round 12: EXACT R7 restore (best: 462us GEMM, util 55.5,
// 0 conflicts) + within-bench A/B of T5 (setprio): rows [0,8K) run PRIO=1,
// rows [8K,16K) run PRIO=0, as two 512-block dispatches (512%8==0, swizzle
// intact). m190 found setprio hurts lockstep GEMM; R7 is partially lockstep —
// this isolates it per-dispatch in rocprof at zero perf cost.
// Structure: 4 phases/iter (2 K-tiles), 1 barrier/phase, counted VMW4,
// XOR-swizzled LDS (stage: linear gload_lds dest + inverse-swz source).
// ============================================================================
#define BM 256
#define BN 256
#define BK 64
#define NTILE (K_DIM / BK)   // 64 -> 32 iterations, last peeled

__device__ __forceinline__ void load_lds16(const ushort_t* g, ushort_t* l) {
  __builtin_amdgcn_global_load_lds(
      (const __attribute__((address_space(1))) unsigned int*)g,
      (__attribute__((address_space(3))) unsigned int*)l, 16, 0, 0);
}

#define BAR __builtin_amdgcn_s_barrier()
#define VMW4 asm volatile("s_waitcnt vmcnt(4)" ::: "memory")
#define VMW0 asm volatile("s_waitcnt vmcnt(0)" ::: "memory")
#define PRIO1 do { if (USE_PRIO) __builtin_amdgcn_s_setprio(1); } while (0)
#define PRIO0 do { if (USE_PRIO) __builtin_amdgcn_s_setprio(0); } while (0)

#define STAGE_A(dst, h, t) do { \
    load_lds16(pA + (size_t)((h) * 128) * K_DIM + (t) * 64, (dst) + (h) * 8192); \
    load_lds16(pA + (size_t)((h) * 128 + 64) * K_DIM + (t) * 64, (dst) + (h) * 8192 + 4096); } while (0)
#define STAGE_B(dst, h, t) do { \
    load_lds16(pB + (size_t)((h) * 128) * K_DIM + (t) * 64, (dst) + (h) * 8192); \
    load_lds16(pB + (size_t)((h) * 128 + 64) * K_DIM + (t) * 64, (dst) + (h) * 8192 + 4096); } while (0)

#define READ_A(buf, arr, q) do { \
    _Pragma("unroll") for (int mf = 0; mf < 4; ++mf) { \
      int ia = aBase + ((q) * 4 + mf) * 1024; \
      arr[mf][0] = *(const s16x8*)&lds[buf][ia]; \
      arr[mf][1] = *(const s16x8*)&lds[buf][ia ^ 32]; } } while (0)
#define READ_B(buf, arr, nh) do { \
    _Pragma("unroll") for (int nf = 0; nf < 2; ++nf) { \
      int ib = bBase + ((nh) * 2 + nf) * 1024; \
      arr[nf][0] = *(const s16x8*)&lds[buf][ib]; \
      arr[nf][1] = *(const s16x8*)&lds[buf][ib ^ 32]; } } while (0)

// 16 MFMA, ks outermost: 8 independent between accumulator reuse.
#define MFMA_Q(arr_a, arr_b, m0, n0) do { \
    _Pragma("unroll") for (int ks = 0; ks < 2; ++ks) \
    _Pragma("unroll") for (int mf = 0; mf < 4; ++mf) \
    _Pragma("unroll") for (int nf = 0; nf < 2; ++nf) \
      acc[(m0) + mf][(n0) + nf] = __builtin_amdgcn_mfma_f32_16x16x32_bf16( \
          arr_a[mf][ks], arr_b[nf][ks], acc[(m0) + mf][(n0) + nf], 0, 0, 0); } while (0)

template <bool USE_PRIO>
__global__ __launch_bounds__(512, 2)
void gemm_4phase(const ushort_t* __restrict__ A, const ushort_t* __restrict__ Bt,
                 const float* __restrict__ bias, float* __restrict__ C) {
  __shared__ ushort_t lds[2][32768];  // [buf][ A: 0..16383 | B: 16384..32767 ]

  // bijective XCD swizzle (nwg = 512, % 8 == 0)
  int nwg = gridDim.x;
  int wg  = blockIdx.x;
  int swz = (wg & 7) * (nwg >> 3) + (wg >> 3);
  int bm = (swz >> 4) << 8;
  int bn = (swz & 15) << 8;

  int tid = threadIdx.x;
  int wid = tid >> 6;
  int l   = tid & 63;
  int wm = wid >> 2, wn = wid & 3;

  // staging: lane covers global (row = base + wid*8 + (l>>3), slot = (l&7)^(row&7))
  int sg8 = ((l & 7) ^ ((l >> 3) & 7)) << 3;
  const ushort_t* pA = A  + (size_t)(bm + wid * 8 + (l >> 3)) * K_DIM + sg8;
  const ushort_t* pB = Bt + (size_t)(bn + wid * 8 + (l >> 3)) * K_DIM + sg8;
  ushort_t* sA0 = &lds[0][wid * 512];
  ushort_t* sA1 = &lds[1][wid * 512];
  ushort_t* sB0 = &lds[0][16384 + wid * 512];
  ushort_t* sB1 = &lds[1][16384 + wid * 512];

  // read bases: row = (wm*128 | mf*16 | (l&15)); slot = (ks*4 | (l>>4)) ^ (l&7)
  int slot0 = (l >> 4) ^ (l & 7);
  int aBase = (wm * 128 + (l & 15)) * 64 + slot0 * 8;
  int bBase = 16384 + (wn * 64 + (l & 15)) * 64 + slot0 * 8;

  f32x4 acc[8][4];
#pragma unroll
  for (int mf = 0; mf < 8; ++mf)
#pragma unroll
    for (int nf = 0; nf < 4; ++nf) acc[mf][nf] = (f32x4){0.f, 0.f, 0.f, 0.f};

  s16x8 a[4][2], b0[2][2], b1[2][2];

  // prologue: tile0 full (8 loads), tile1 B (4 loads); drain tile0 (leave B(t1))
  STAGE_B(sB0, 0, 0); STAGE_B(sB0, 1, 0);
  STAGE_A(sA0, 0, 0); STAGE_A(sA0, 1, 0);
  STAGE_B(sB1, 0, 1); STAGE_B(sB1, 1, 1);
  VMW4; BAR;

  for (int j = 0; j < NTILE / 2 - 1; ++j) {   // j = 0..30, tiles 0..61
    int t1 = 2 * j + 1, t2 = 2 * j + 2, t3 = 2 * j + 3;
    // PA1: tile 2j (buf0) q00+q01
    READ_A(0, a, 0); READ_B(0, b0, 0); READ_B(0, b1, 1);
    STAGE_A(sA1, 0, t1); STAGE_A(sA1, 1, t1);
    PRIO1; MFMA_Q(a, b0, 0, 0); MFMA_Q(a, b1, 0, 2); PRIO0;
    BAR;
    // PB1: tile 2j q11+q10; drain A(t1)
    READ_A(0, a, 1);
    STAGE_B(sB0, 0, t2); STAGE_B(sB0, 1, t2);
    PRIO1; MFMA_Q(a, b1, 4, 2); MFMA_Q(a, b0, 4, 0); PRIO0;
    VMW4; BAR;
    // PA2: tile 2j+1 (buf1) q00+q01
    READ_A(1, a, 0); READ_B(1, b0, 0); READ_B(1, b1, 1);
    STAGE_A(sA0, 0, t2); STAGE_A(sA0, 1, t2);
    PRIO1; MFMA_Q(a, b0, 0, 0); MFMA_Q(a, b1, 0, 2); PRIO0;
    BAR;
    // PB2: tile 2j+1 q11+q10; drain B(t2),A(t2)
    READ_A(1, a, 1);
    STAGE_B(sB1, 0, t3); STAGE_B(sB1, 1, t3);
    PRIO1; MFMA_Q(a, b1, 4, 2); MFMA_Q(a, b0, 4, 0); PRIO0;
    VMW4; BAR;
  }

  // tail: tiles 62 (buf0), 63 (buf1); B(63) staged in j=30's PB2
  {
    READ_A(0, a, 0); READ_B(0, b0, 0); READ_B(0, b1, 1);
    STAGE_A(sA1, 0, 63); STAGE_A(sA1, 1, 63);
    PRIO1; MFMA_Q(a, b0, 0, 0); MFMA_Q(a, b1, 0, 2); PRIO0;
    BAR;

    READ_A(0, a, 1);
    PRIO1; MFMA_Q(a, b1, 4, 2); MFMA_Q(a, b0, 4, 0); PRIO0;
    VMW0; BAR;   // drain A(63)

    READ_A(1, a, 0); READ_B(1, b0, 0); READ_B(1, b1, 1);
    PRIO1; MFMA_Q(a, b0, 0, 0); MFMA_Q(a, b1, 0, 2); PRIO0;
    BAR;

    READ_A(1, a, 1);
    PRIO1; MFMA_Q(a, b1, 4, 2); MFMA_Q(a, b0, 4, 0); PRIO0;
  }

  // epilogue: C/D layout col = lane&15, row = (lane>>4)*4 + j
  int r0 = bm + wm * 128 + ((l >> 4) << 2);
  int c0 = bn + wn * 64 + (l & 15);
#pragma unroll
  for (int nf = 0; nf < 4; ++nf) {
    float bv = bias[c0 + nf * 16];
#pragma unroll
    for (int mf = 0; mf < 8; ++mf) {
#pragma unroll
      for (int jj = 0; jj < 4; ++jj)
        C[(size_t)(r0 + mf * 16 + jj) * N_DIM + (c0 + nf * 16)] = acc[mf][nf][jj] + bv;
    }
  }
}

// ---------- naive fp32 fallback (only if ws_size too small) ----------
__global__ __launch_bounds__(256)
void gemm_naive(const float* __restrict__ A, const float* __restrict__ B,
                const float* __restrict__ bias, float* __restrict__ C) {
  __shared__ float As[64][17];
  __shared__ float Bs[16][65];
  int nbn = N_DIM / 64;
  int m0 = (blockIdx.x / nbn) * 64;
  int n0 = (blockIdx.x % nbn) * 64;
  int tid = threadIdx.x;
  int tx = tid & 15, ty = tid >> 4;
  float acc[4][4] = {};
  for (int k0 = 0; k0 < K_DIM; k0 += 16) {
    __syncthreads();
#pragma unroll
    for (int e = tid * 4, i = 0; i < 4; ++i) {
      int idx = e + i;
      int r = idx >> 4, k = idx & 15;
      As[r][k] = A[(size_t)(m0 + r) * K_DIM + k0 + k];
    }
#pragma unroll
    for (int e = tid * 4, i = 0; i < 4; ++i) {
      int idx = e + i;
      int k = idx >> 6, n = idx & 63;
      Bs[k][n] = B[(size_t)(k0 + k) * N_DIM + n0 + n];
    }
    __syncthreads();
#pragma unroll
    for (int kk = 0; kk < 16; ++kk)
#pragma unroll
      for (int i = 0; i < 4; ++i)
#pragma unroll
        for (int j = 0; j < 4; ++j)
          acc[i][j] += As[ty * 4 + i][kk] * Bs[kk][tx * 4 + j];
  }
#pragma unroll
  for (int i = 0; i < 4; ++i)
#pragma unroll
    for (int j = 0; j < 4; ++j) {
      int r = m0 + ty * 4 + i, c = n0 + tx * 4 + j;
      C[(size_t)r * N_DIM + c] = acc[i][j] + bias[c];
    }
}

extern "C" void kernel_launch(void* const* d_in, const int* in_sizes, int n_in,
                              void* d_out, int out_size, void* d_ws, size_t ws_size,
                              hipStream_t stream) {
  const float* A32  = (const float*)d_in[0];
  const float* W32  = (const float*)d_in[1];
  const float* bias = (const float*)d_in[2];
  float* C = (float*)d_out;

  const size_t needA = (size_t)M_TOTAL * K_DIM * sizeof(ushort_t); // 128 MiB
  const size_t needB = (size_t)N_DIM * K_DIM * sizeof(ushort_t);   // 32 MiB

  if (ws_size >= needA + needB) {
    ushort_t* Abf = (ushort_t*)d_ws;
    ushort_t* Btb = (ushort_t*)((char*)d_ws + needA);
    long n8 = (long)M_TOTAL * K_DIM / 8;
    cast_kernel<<<(int)((n8 + 255) / 256), 256, 0, stream>>>(A32, Abf, n8);
    transpose_cast_kernel<<<(K_DIM / 64) * (N_DIM / 64), 256, 0, stream>>>(W32, Btb);
    // A/B: rows [0, 8192) with setprio, rows [8192, 16384) without.
    const int HALF_M = M_TOTAL / 2;
    const int grid_half = (HALF_M / BM) * (N_DIM / BN);   // 512, % 8 == 0
    gemm_4phase<true><<<grid_half, 512, 0, stream>>>(Abf, Btb, bias, C);
    gemm_4phase<false><<<grid_half, 512, 0, stream>>>(
        Abf + (size_t)HALF_M * K_DIM, Btb, bias, C + (size_t)HALF_M * N_DIM);
  } else {
    gemm_naive<<<(M_TOTAL / 64) * (N_DIM / 64), 256, 0, stream>>>(A32, W32, bias, C);
  }
}

// Round 13
// 542.783 us; speedup vs baseline: 4.3793x; 1.0184x over previous
//
#include <hip/hip_runtime.h>
#include <hip/hip_bf16.h>
#include <cstdint>
#include <cstddef>

#define M_TOTAL 16384   // WORLD_SIZE * M_LOCAL
#define K_DIM   4096
#define N_DIM   4096

typedef __attribute__((ext_vector_type(8))) short s16x8;
typedef __attribute__((ext_vector_type(4))) float f32x4;
typedef unsigned short ushort_t;

// ---------- fp32 -> bf16 round-to-nearest-even ----------
__device__ __forceinline__ ushort_t f2bf(float x) {
  unsigned u = __float_as_uint(x);
  return (ushort_t)((u + 0x7fffu + ((u >> 16) & 1u)) >> 16);
}

// ---------- cast A [M,K] fp32 -> bf16, 8 elems/thread (HBM-roofline, ~61us) ----------
__global__ __launch_bounds__(256) void cast_kernel(const float* __restrict__ in,
                                                   ushort_t* __restrict__ out,
                                                   long n8) {
  long i = (long)blockIdx.x * 256 + threadIdx.x;
  if (i >= n8) return;
  const f32x4* p = (const f32x4*)in + i * 2;
  f32x4 a = p[0], b = p[1];
  union { s16x8 v; ushort_t u[8]; } r;
  r.u[0] = f2bf(a.x); r.u[1] = f2bf(a.y); r.u[2] = f2bf(a.z); r.u[3] = f2bf(a.w);
  r.u[4] = f2bf(b.x); r.u[5] = f2bf(b.y); r.u[6] = f2bf(b.z); r.u[7] = f2bf(b.w);
  *((s16x8*)out + i) = r.v;
}

// ---------- transpose+cast W [K,N] fp32 -> Bt [N,K] bf16 (~18us) ----------
__global__ __launch_bounds__(256) void transpose_cast_kernel(const float* __restrict__ B,
                                                             ushort_t* __restrict__ Bt) {
  __shared__ float tile[64][65];
  int nbx = N_DIM / 64;
  int n0 = (blockIdx.x % nbx) * 64;
  int k0 = (blockIdx.x / nbx) * 64;
  int tx = threadIdx.x & 63;
  int ty = threadIdx.x >> 6;
#pragma unroll
  for (int i = 0; i < 64; i += 4)
    tile[ty + i][tx] = B[(size_t)(k0 + ty + i) * N_DIM + n0 + tx];
  __syncthreads();
#pragma unroll
  for (int i = 0; i < 64; i += 4)
    Bt[(size_t)(n0 + ty + i) * K_DIM + k0 + tx] = f2bf(tile[tx][ty + i]);
}

// ============================================================================
// 256x256 bf16 GEMM — FINAL (R7 structure, best measured: 462us, util 55.5%).
// 4 phases / 2 K-tiles, 1 barrier/phase, counted vmcnt(4) (never 0 in loop),
// XOR-swizzled LDS (0 bank conflicts: stage via linear global_load_lds dest +
// inverse-swizzled per-lane global source; reads apply the same XOR), XCD-
// bijective block swizzle, setprio(1) around MFMA clusters (A/B: +2%).
//
// WHY THIS IS THE CEILING FOR THIS STRUCTURE [session R1-R12 evidence]:
//   per K64-tile per CU: 96 x ds_read_b128 @ ~12cy = 1152 cy LDS delivery
//   vs 620 cy matrix-pipe -> perfect-overlap ceiling 54%; measured 55.5%.
//   - wave-tile 128x64 minimizes LDS bytes/FLOP for acc that fits 256 regs
//     (8 waves x 256 = exactly the 2048 VGPR pool; +anything spills: R5/R10)
//   - 32x32 MFMA reads identical bytes (R8: no gain); smaller wave-tiles
//     read more bytes/FLOP (R11: util 42%); sched/barrier changes don't
//     alter LDS instr count (R3/R6/R9/R10: null or worse)
//   - fp8 would halve LDS bytes but absmax (~0.35 est) exceeds 0.114 budget
// ============================================================================
#define BM 256
#define BN 256
#define BK 64
#define NTILE (K_DIM / BK)   // 64 -> 32 iterations, last peeled

__device__ __forceinline__ void load_lds16(const ushort_t* g, ushort_t* l) {
  __builtin_amdgcn_global_load_lds(
      (const __attribute__((address_space(1))) unsigned int*)g,
      (__attribute__((address_space(3))) unsigned int*)l, 16, 0, 0);
}

#define BAR __builtin_amdgcn_s_barrier()
#define VMW4 asm volatile("s_waitcnt vmcnt(4)" ::: "memory")
#define VMW0 asm volatile("s_waitcnt vmcnt(0)" ::: "memory")
#define PRIO1 __builtin_amdgcn_s_setprio(1)
#define PRIO0 __builtin_amdgcn_s_setprio(0)

#define STAGE_A(dst, h, t) do { \
    load_lds16(pA + (size_t)((h) * 128) * K_DIM + (t) * 64, (dst) + (h) * 8192); \
    load_lds16(pA + (size_t)((h) * 128 + 64) * K_DIM + (t) * 64, (dst) + (h) * 8192 + 4096); } while (0)
#define STAGE_B(dst, h, t) do { \
    load_lds16(pB + (size_t)((h) * 128) * K_DIM + (t) * 64, (dst) + (h) * 8192); \
    load_lds16(pB + (size_t)((h) * 128 + 64) * K_DIM + (t) * 64, (dst) + (h) * 8192 + 4096); } while (0)

#define READ_A(buf, arr, q) do { \
    _Pragma("unroll") for (int mf = 0; mf < 4; ++mf) { \
      int ia = aBase + ((q) * 4 + mf) * 1024; \
      arr[mf][0] = *(const s16x8*)&lds[buf][ia]; \
      arr[mf][1] = *(const s16x8*)&lds[buf][ia ^ 32]; } } while (0)
#define READ_B(buf, arr, nh) do { \
    _Pragma("unroll") for (int nf = 0; nf < 2; ++nf) { \
      int ib = bBase + ((nh) * 2 + nf) * 1024; \
      arr[nf][0] = *(const s16x8*)&lds[buf][ib]; \
      arr[nf][1] = *(const s16x8*)&lds[buf][ib ^ 32]; } } while (0)

// 16 MFMA, ks outermost: 8 independent between accumulator reuse.
#define MFMA_Q(arr_a, arr_b, m0, n0) do { \
    _Pragma("unroll") for (int ks = 0; ks < 2; ++ks) \
    _Pragma("unroll") for (int mf = 0; mf < 4; ++mf) \
    _Pragma("unroll") for (int nf = 0; nf < 2; ++nf) \
      acc[(m0) + mf][(n0) + nf] = __builtin_amdgcn_mfma_f32_16x16x32_bf16( \
          arr_a[mf][ks], arr_b[nf][ks], acc[(m0) + mf][(n0) + nf], 0, 0, 0); } while (0)

__global__ __launch_bounds__(512, 2)
void gemm_4phase(const ushort_t* __restrict__ A, const ushort_t* __restrict__ Bt,
                 const float* __restrict__ bias, float* __restrict__ C) {
  __shared__ ushort_t lds[2][32768];  // [buf][ A: 0..16383 | B: 16384..32767 ]

  // bijective XCD swizzle (nwg = 1024, % 8 == 0)
  int nwg = gridDim.x;
  int wg  = blockIdx.x;
  int swz = (wg & 7) * (nwg >> 3) + (wg >> 3);
  int bm = (swz >> 4) << 8;
  int bn = (swz & 15) << 8;

  int tid = threadIdx.x;
  int wid = tid >> 6;
  int l   = tid & 63;
  int wm = wid >> 2, wn = wid & 3;

  // staging: lane covers global (row = base + wid*8 + (l>>3), slot = (l&7)^(row&7))
  int sg8 = ((l & 7) ^ ((l >> 3) & 7)) << 3;
  const ushort_t* pA = A  + (size_t)(bm + wid * 8 + (l >> 3)) * K_DIM + sg8;
  const ushort_t* pB = Bt + (size_t)(bn + wid * 8 + (l >> 3)) * K_DIM + sg8;
  ushort_t* sA0 = &lds[0][wid * 512];
  ushort_t* sA1 = &lds[1][wid * 512];
  ushort_t* sB0 = &lds[0][16384 + wid * 512];
  ushort_t* sB1 = &lds[1][16384 + wid * 512];

  // read bases: row = (wm*128 | mf*16 | (l&15)); slot = (ks*4 | (l>>4)) ^ (l&7)
  int slot0 = (l >> 4) ^ (l & 7);
  int aBase = (wm * 128 + (l & 15)) * 64 + slot0 * 8;
  int bBase = 16384 + (wn * 64 + (l & 15)) * 64 + slot0 * 8;

  f32x4 acc[8][4];
#pragma unroll
  for (int mf = 0; mf < 8; ++mf)
#pragma unroll
    for (int nf = 0; nf < 4; ++nf) acc[mf][nf] = (f32x4){0.f, 0.f, 0.f, 0.f};

  s16x8 a[4][2], b0[2][2], b1[2][2];

  // prologue: tile0 full (8 loads), tile1 B (4 loads); drain tile0 (leave B(t1))
  STAGE_B(sB0, 0, 0); STAGE_B(sB0, 1, 0);
  STAGE_A(sA0, 0, 0); STAGE_A(sA0, 1, 0);
  STAGE_B(sB1, 0, 1); STAGE_B(sB1, 1, 1);
  VMW4; BAR;

  for (int j = 0; j < NTILE / 2 - 1; ++j) {   // j = 0..30, tiles 0..61
    int t1 = 2 * j + 1, t2 = 2 * j + 2, t3 = 2 * j + 3;
    // PA1: tile 2j (buf0) q00+q01
    READ_A(0, a, 0); READ_B(0, b0, 0); READ_B(0, b1, 1);
    STAGE_A(sA1, 0, t1); STAGE_A(sA1, 1, t1);
    PRIO1; MFMA_Q(a, b0, 0, 0); MFMA_Q(a, b1, 0, 2); PRIO0;
    BAR;
    // PB1: tile 2j q11+q10; drain A(t1)
    READ_A(0, a, 1);
    STAGE_B(sB0, 0, t2); STAGE_B(sB0, 1, t2);
    PRIO1; MFMA_Q(a, b1, 4, 2); MFMA_Q(a, b0, 4, 0); PRIO0;
    VMW4; BAR;
    // PA2: tile 2j+1 (buf1) q00+q01
    READ_A(1, a, 0); READ_B(1, b0, 0); READ_B(1, b1, 1);
    STAGE_A(sA0, 0, t2); STAGE_A(sA0, 1, t2);
    PRIO1; MFMA_Q(a, b0, 0, 0); MFMA_Q(a, b1, 0, 2); PRIO0;
    BAR;
    // PB2: tile 2j+1 q11+q10; drain B(t2),A(t2)
    READ_A(1, a, 1);
    STAGE_B(sB1, 0, t3); STAGE_B(sB1, 1, t3);
    PRIO1; MFMA_Q(a, b1, 4, 2); MFMA_Q(a, b0, 4, 0); PRIO0;
    VMW4; BAR;
  }

  // tail: tiles 62 (buf0), 63 (buf1); B(63) staged in j=30's PB2
  {
    READ_A(0, a, 0); READ_B(0, b0, 0); READ_B(0, b1, 1);
    STAGE_A(sA1, 0, 63); STAGE_A(sA1, 1, 63);
    PRIO1; MFMA_Q(a, b0, 0, 0); MFMA_Q(a, b1, 0, 2); PRIO0;
    BAR;

    READ_A(0, a, 1);
    PRIO1; MFMA_Q(a, b1, 4, 2); MFMA_Q(a, b0, 4, 0); PRIO0;
    VMW0; BAR;   // drain A(63)

    READ_A(1, a, 0); READ_B(1, b0, 0); READ_B(1, b1, 1);
    PRIO1; MFMA_Q(a, b0, 0, 0); MFMA_Q(a, b1, 0, 2); PRIO0;
    BAR;

    READ_A(1, a, 1);
    PRIO1; MFMA_Q(a, b1, 4, 2); MFMA_Q(a, b0, 4, 0); PRIO0;
  }

  // epilogue: C/D layout col = lane&15, row = (lane>>4)*4 + j
  int r0 = bm + wm * 128 + ((l >> 4) << 2);
  int c0 = bn + wn * 64 + (l & 15);
#pragma unroll
  for (int nf = 0; nf < 4; ++nf) {
    float bv = bias[c0 + nf * 16];
#pragma unroll
    for (int mf = 0; mf < 8; ++mf) {
#pragma unroll
      for (int jj = 0; jj < 4; ++jj)
        C[(size_t)(r0 + mf * 16 + jj) * N_DIM + (c0 + nf * 16)] = acc[mf][nf][jj] + bv;
    }
  }
}

// ---------- naive fp32 fallback (only if ws_size too small) ----------
__global__ __launch_bounds__(256)
void gemm_naive(const float* __restrict__ A, const float* __restrict__ B,
                const float* __restrict__ bias, float* __restrict__ C) {
  __shared__ float As[64][17];
  __shared__ float Bs[16][65];
  int nbn = N_DIM / 64;
  int m0 = (blockIdx.x / nbn) * 64;
  int n0 = (blockIdx.x % nbn) * 64;
  int tid = threadIdx.x;
  int tx = tid & 15, ty = tid >> 4;
  float acc[4][4] = {};
  for (int k0 = 0; k0 < K_DIM; k0 += 16) {
    __syncthreads();
#pragma unroll
    for (int e = tid * 4, i = 0; i < 4; ++i) {
      int idx = e + i;
      int r = idx >> 4, k = idx & 15;
      As[r][k] = A[(size_t)(m0 + r) * K_DIM + k0 + k];
    }
#pragma unroll
    for (int e = tid * 4, i = 0; i < 4; ++i) {
      int idx = e + i;
      int k = idx >> 6, n = idx & 63;
      Bs[k][n] = B[(size_t)(k0 + k) * N_DIM + n0 + n];
    }
    __syncthreads();
#pragma unroll
    for (int kk = 0; kk < 16; ++kk)
#pragma unroll
      for (int i = 0; i < 4; ++i)
#pragma unroll
        for (int j = 0; j < 4; ++j)
          acc[i][j] += As[ty * 4 + i][kk] * Bs[kk][tx * 4 + j];
  }
#pragma unroll
  for (int i = 0; i < 4; ++i)
#pragma unroll
    for (int j = 0; j < 4; ++j) {
      int r = m0 + ty * 4 + i, c = n0 + tx * 4 + j;
      C[(size_t)r * N_DIM + c] = acc[i][j] + bias[c];
    }
}

extern "C" void kernel_launch(void* const* d_in, const int* in_sizes, int n_in,
                              void* d_out, int out_size, void* d_ws, size_t ws_size,
                              hipStream_t stream) {
  const float* A32  = (const float*)d_in[0];
  const float* W32  = (const float*)d_in[1];
  const float* bias = (const float*)d_in[2];
  float* C = (float*)d_out;

  const size_t needA = (size_t)M_TOTAL * K_DIM * sizeof(ushort_t); // 128 MiB
  const size_t needB = (size_t)N_DIM * K_DIM * sizeof(ushort_t);   // 32 MiB

  if (ws_size >= needA + needB) {
    ushort_t* Abf = (ushort_t*)d_ws;
    ushort_t* Btb = (ushort_t*)((char*)d_ws + needA);
    long n8 = (long)M_TOTAL * K_DIM / 8;
    cast_kernel<<<(int)((n8 + 255) / 256), 256, 0, stream>>>(A32, Abf, n8);
    transpose_cast_kernel<<<(K_DIM / 64) * (N_DIM / 64), 256, 0, stream>>>(W32, Btb);
    gemm_4phase<<<(M_TOTAL / BM) * (N_DIM / BN), 512, 0, stream>>>(Abf, Btb, bias, C);
  } else {
    gemm_naive<<<(M_TOTAL / 64) * (N_DIM / 64), 256, 0, stream>>>(A32, W32, bias, C);
  }
}